// Round 1
// baseline (238.650 us; speedup 1.0000x reference)
//
#include <hip/hip_runtime.h>
#include <cstdint>
#include <cstddef>

#define B_   8
#define S_   1024
#define H_   1024
#define NH_  16
#define HD_  64
#define M_   8192   // B*S
#define N3_  3072   // 3*H
#define K_   1024

typedef __attribute__((ext_vector_type(8))) short bf16x8;
typedef __attribute__((ext_vector_type(4))) float f32x4;
typedef __attribute__((ext_vector_type(8))) unsigned short u16x8;

__device__ __forceinline__ unsigned short f2bf(float f) {
  unsigned u = __builtin_bit_cast(unsigned, f);
  u += 0x7fffu + ((u >> 16) & 1u);      // round-to-nearest-even (finite inputs)
  return (unsigned short)(u >> 16);
}

// ---------------- fp32 -> bf16 pack ----------------
__global__ void cvt_kernel(const float* __restrict__ src,
                           unsigned short* __restrict__ dst, int n) {
  const int stride = gridDim.x * blockDim.x * 8;
  for (int i = (blockIdx.x * blockDim.x + threadIdx.x) * 8; i < n; i += stride) {
    float4 a = *reinterpret_cast<const float4*>(src + i);
    float4 b = *reinterpret_cast<const float4*>(src + i + 4);
    u16x8 o;
    o[0] = f2bf(a.x); o[1] = f2bf(a.y); o[2] = f2bf(a.z); o[3] = f2bf(a.w);
    o[4] = f2bf(b.x); o[5] = f2bf(b.y); o[6] = f2bf(b.z); o[7] = f2bf(b.w);
    *reinterpret_cast<u16x8*>(dst + i) = o;
  }
}

// ---------------- fused QKV GEMM ----------------
// C[i,o] = sum_k act[i,k] * W[o,k] + bias[o]   (both operands K-contiguous)
// 128x128 tile, BK=64, 4 waves (2x2) of 64x64, mfma_f32_16x16x32_bf16.
// LDS linear-dest global_load_lds + inverse-swizzled SOURCE; reads XOR-swizzled.
#define BM 128
#define BN 128
#define BK 64

__global__ __launch_bounds__(256) void qkv_gemm(
    const unsigned short* __restrict__ A,    // [8192][1024] bf16
    const unsigned short* __restrict__ Bw,   // [3072][1024] bf16 (qw|kw|vw rows)
    const float* __restrict__ qb, const float* __restrict__ kb,
    const float* __restrict__ vb,
    unsigned short* __restrict__ Qh,   // [128][1024][64], pre-scaled by 1/32
    unsigned short* __restrict__ Kh,   // [128][1024][64]
    unsigned short* __restrict__ Vth)  // [128][64][1024]  (V transposed)
{
  __shared__ unsigned short As[BM * BK];
  __shared__ unsigned short Bs[BN * BK];
  const int t = threadIdx.x;
  const int lane = t & 63;
  const int bm = blockIdx.x, bn = blockIdx.y;
  const int wm = t >> 7, wn = (t >> 6) & 1;

  f32x4 acc[4][4] = {};

  const char* Ab = (const char*)(A + (size_t)bm * BM * K_);
  const char* Bb = (const char*)(Bw + (size_t)bn * BN * K_);

  for (int kt = 0; kt < K_ / BK; ++kt) {
    const int k0b = kt * BK * 2;  // byte offset along K
    #pragma unroll
    for (int i = 0; i < 4; ++i) {
      const int off = (i * 256 + t) * 16;     // byte offset in 16KB tile
      const int row = off >> 7;               // 128B per row (64 bf16)
      const int c16 = (off >> 4) & 7;         // 16B chunk within row
      const int sc  = c16 ^ (row & 7);        // inverse swizzle on SOURCE
      __builtin_amdgcn_global_load_lds(
          (const __attribute__((address_space(1))) void*)(Ab + (size_t)row * (K_ * 2) + k0b + sc * 16),
          (__attribute__((address_space(3))) void*)((char*)As + off), 16, 0, 0);
      __builtin_amdgcn_global_load_lds(
          (const __attribute__((address_space(1))) void*)(Bb + (size_t)row * (K_ * 2) + k0b + sc * 16),
          (__attribute__((address_space(3))) void*)((char*)Bs + off), 16, 0, 0);
    }
    __syncthreads();

    #pragma unroll
    for (int kk = 0; kk < 2; ++kk) {
      bf16x8 af[4], bfr[4];
      #pragma unroll
      for (int mb = 0; mb < 4; ++mb) {
        const int row = wm * 64 + mb * 16 + (lane & 15);
        const int j   = kk * 4 + (lane >> 4);
        af[mb] = *reinterpret_cast<const bf16x8*>(
            (const char*)As + row * 128 + ((j ^ (row & 7)) << 4));
      }
      #pragma unroll
      for (int nb = 0; nb < 4; ++nb) {
        const int row = wn * 64 + nb * 16 + (lane & 15);
        const int j   = kk * 4 + (lane >> 4);
        bfr[nb] = *reinterpret_cast<const bf16x8*>(
            (const char*)Bs + row * 128 + ((j ^ (row & 7)) << 4));
      }
      #pragma unroll
      for (int mb = 0; mb < 4; ++mb)
        #pragma unroll
        for (int nb = 0; nb < 4; ++nb)
          acc[mb][nb] = __builtin_amdgcn_mfma_f32_16x16x32_bf16(
              af[mb], bfr[nb], acc[mb][nb], 0, 0, 0);
    }
    __syncthreads();
  }

  // epilogue: bias, scale Q by 1/32, scatter head-major (V transposed)
  const int grow = bm * BM + wm * 64;
  const int gcol = bn * BN + wn * 64;
  #pragma unroll
  for (int nb = 0; nb < 4; ++nb) {
    const int col = gcol + nb * 16 + (lane & 15);  // 0..3071
    const int tensor = col >> 10;                  // 0=q 1=k 2=v
    const int o  = col & 1023;
    const int nh = o >> 6, hd = o & 63;
    const float* bias = (tensor == 0) ? qb : (tensor == 1) ? kb : vb;
    const float bv  = bias[o];
    const float scl = (tensor == 0) ? 0.03125f : 1.0f;  // 1/sqrt(1024)
    #pragma unroll
    for (int mb = 0; mb < 4; ++mb) {
      #pragma unroll
      for (int r = 0; r < 4; ++r) {
        const int i  = grow + mb * 16 + (lane >> 4) * 4 + r;   // row index
        const int bb = i >> 10, s = i & 1023;
        const unsigned short h = f2bf((acc[mb][nb][r] + bv) * scl);
        const int bhn = bb * NH_ + nh;
        if (tensor == 0)      Qh[((size_t)bhn * S_ + s) * HD_ + hd] = h;
        else if (tensor == 1) Kh[((size_t)bhn * S_ + s) * HD_ + hd] = h;
        else                  Vth[((size_t)bhn * HD_ + hd) * S_ + s] = h;
      }
    }
  }
}

// ---------------- flash attention ----------------
// block = (q-tile of 128 rows) x (one of 128 heads); 4 waves x 32 q-rows.
// K/V read directly from global (L2-resident, 256KB/head). P via per-wave
// XOR-swizzled LDS round-trip to reach MFMA A-layout.
__global__ __launch_bounds__(256) void attn_kernel(
    const unsigned short* __restrict__ Qh,
    const unsigned short* __restrict__ Kh,
    const unsigned short* __restrict__ Vth,
    float* __restrict__ Out)
{
  __shared__ unsigned short Pl[4][32 * 64];
  const int t = threadIdx.x;
  const int lane = t & 63;
  const int wave = t >> 6;
  const int qt = blockIdx.x;      // 0..7
  const int bh = blockIdx.y;      // 0..127
  const int b = bh >> 4, nh = bh & 15;

  const unsigned short* Qp = Qh + (size_t)bh * (S_ * HD_);
  const unsigned short* Kp = Kh + (size_t)bh * (S_ * HD_);
  const unsigned short* Vp = Vth + (size_t)bh * (S_ * HD_);

  const int q0 = qt * 128 + wave * 32;

  // hoist Q fragments (already scaled by 1/32)
  bf16x8 aq[2][2];
  #pragma unroll
  for (int mb = 0; mb < 2; ++mb)
    #pragma unroll
    for (int kk = 0; kk < 2; ++kk)
      aq[mb][kk] = *reinterpret_cast<const bf16x8*>(
          Qp + (size_t)(q0 + mb * 16 + (lane & 15)) * HD_ + kk * 32 + (lane >> 4) * 8);

  float m_run[2][4], l_run[2][4];
  f32x4 o_acc[2][4] = {};
  #pragma unroll
  for (int mb = 0; mb < 2; ++mb)
    #pragma unroll
    for (int r = 0; r < 4; ++r) { m_run[mb][r] = -1e30f; l_run[mb][r] = 0.f; }

  unsigned short* myP = &Pl[wave][0];

  for (int kt = 0; kt < S_ / 64; ++kt) {
    // ---- QK^T: S[32 q][64 keys] per wave ----
    f32x4 sc[2][4] = {};
    #pragma unroll
    for (int kk = 0; kk < 2; ++kk) {
      #pragma unroll
      for (int nb = 0; nb < 4; ++nb) {
        bf16x8 bk = *reinterpret_cast<const bf16x8*>(
            Kp + (size_t)(kt * 64 + nb * 16 + (lane & 15)) * HD_ + kk * 32 + (lane >> 4) * 8);
        sc[0][nb] = __builtin_amdgcn_mfma_f32_16x16x32_bf16(aq[0][kk], bk, sc[0][nb], 0, 0, 0);
        sc[1][nb] = __builtin_amdgcn_mfma_f32_16x16x32_bf16(aq[1][kk], bk, sc[1][nb], 0, 0, 0);
      }
    }
    // ---- online softmax (wave-parallel, 16-lane row groups) ----
    #pragma unroll
    for (int mb = 0; mb < 2; ++mb) {
      #pragma unroll
      for (int r = 0; r < 4; ++r) {
        float mx = fmaxf(fmaxf(sc[mb][0][r], sc[mb][1][r]),
                         fmaxf(sc[mb][2][r], sc[mb][3][r]));
        #pragma unroll
        for (int d = 1; d < 16; d <<= 1) mx = fmaxf(mx, __shfl_xor(mx, d));
        const float mn = fmaxf(m_run[mb][r], mx);
        const float alpha = __expf(m_run[mb][r] - mn);
        m_run[mb][r] = mn;
        float sum = 0.f;
        #pragma unroll
        for (int nb = 0; nb < 4; ++nb) {
          const float p = __expf(sc[mb][nb][r] - mn);
          sc[mb][nb][r] = p;
          sum += p;
        }
        #pragma unroll
        for (int d = 1; d < 16; d <<= 1) sum += __shfl_xor(sum, d);
        l_run[mb][r] = l_run[mb][r] * alpha + sum;
        #pragma unroll
        for (int nb = 0; nb < 4; ++nb) o_acc[mb][nb][r] *= alpha;
      }
    }
    // ---- P -> LDS (bf16, XOR-swizzled rows) ----
    #pragma unroll
    for (int mb = 0; mb < 2; ++mb) {
      #pragma unroll
      for (int nb = 0; nb < 4; ++nb) {
        #pragma unroll
        for (int r = 0; r < 4; ++r) {
          const int row = mb * 16 + (lane >> 4) * 4 + r;
          const int col = nb * 16 + (lane & 15);
          const int byo = row * 128 + ((((col >> 3) ^ (row & 7)) << 4) | ((col & 7) << 1));
          *reinterpret_cast<unsigned short*>((char*)myP + byo) = f2bf(sc[mb][nb][r]);
        }
      }
    }
    // ---- PV: O += P[32x64] * V[64 keys x 64 hd] ----
    #pragma unroll
    for (int kk = 0; kk < 2; ++kk) {
      bf16x8 pa[2];
      #pragma unroll
      for (int mb = 0; mb < 2; ++mb) {
        const int row = mb * 16 + (lane & 15);
        const int j   = kk * 4 + (lane >> 4);
        pa[mb] = *reinterpret_cast<const bf16x8*>(
            (const char*)myP + row * 128 + ((j ^ (row & 7)) << 4));
      }
      #pragma unroll
      for (int nb = 0; nb < 4; ++nb) {
        bf16x8 bv = *reinterpret_cast<const bf16x8*>(
            Vp + (size_t)(nb * 16 + (lane & 15)) * S_ + kt * 64 + kk * 32 + (lane >> 4) * 8);
        o_acc[0][nb] = __builtin_amdgcn_mfma_f32_16x16x32_bf16(pa[0], bv, o_acc[0][nb], 0, 0, 0);
        o_acc[1][nb] = __builtin_amdgcn_mfma_f32_16x16x32_bf16(pa[1], bv, o_acc[1][nb], 0, 0, 0);
      }
    }
  }

  // ---- normalize + write fp32 output [B,S,H] ----
  #pragma unroll
  for (int mb = 0; mb < 2; ++mb) {
    #pragma unroll
    for (int r = 0; r < 4; ++r) {
      const float inv = 1.0f / l_run[mb][r];
      const int s = q0 + mb * 16 + (lane >> 4) * 4 + r;
      #pragma unroll
      for (int nb = 0; nb < 4; ++nb) {
        const int hd = nb * 16 + (lane & 15);
        Out[((size_t)(b * S_ + s)) * H_ + nh * HD_ + hd] = o_acc[mb][nb][r] * inv;
      }
    }
  }
}

extern "C" void kernel_launch(void* const* d_in, const int* in_sizes, int n_in,
                              void* d_out, int out_size, void* d_ws, size_t ws_size,
                              hipStream_t stream) {
  const float* act = (const float*)d_in[0];
  const float* qw  = (const float*)d_in[1];
  const float* qb  = (const float*)d_in[2];
  const float* kw  = (const float*)d_in[3];
  const float* kb  = (const float*)d_in[4];
  const float* vw  = (const float*)d_in[5];
  const float* vb  = (const float*)d_in[6];

  char* ws = (char*)d_ws;
  unsigned short* actb = (unsigned short*)ws;                         // 16 MB
  unsigned short* wb   = (unsigned short*)(ws + 16777216);            // 6 MB
  unsigned short* Qh   = (unsigned short*)(ws + 23068672);            // 16 MB
  unsigned short* Kh   = Qh + 8388608;                                // 16 MB
  unsigned short* Vth  = Kh + 8388608;                                // 16 MB

  cvt_kernel<<<4096, 256, 0, stream>>>(act, actb, M_ * K_);
  cvt_kernel<<<512, 256, 0, stream>>>(qw, wb,               H_ * H_);
  cvt_kernel<<<512, 256, 0, stream>>>(kw, wb + 1048576,     H_ * H_);
  cvt_kernel<<<512, 256, 0, stream>>>(vw, wb + 2097152,     H_ * H_);

  dim3 gg(M_ / BM, N3_ / BN);   // 64 x 24
  qkv_gemm<<<gg, 256, 0, stream>>>(actb, wb, qb, kb, vb, Qh, Kh, Vth);

  dim3 ga(S_ / 128, B_ * NH_);  // 8 x 128
  attn_kernel<<<ga, 256, 0, stream>>>(Qh, Kh, Vth, (float*)d_out);
}